// Round 20
// baseline (192.244 us; speedup 1.0000x reference)
//
#include <hip/hip_runtime.h>

#define BTOK 32768   // B*H*W tokens
#define CC 256
#define CC2 512
#define NBATCH 8

typedef __bf16 bf16x8 __attribute__((ext_vector_type(8)));
typedef float f32x4 __attribute__((ext_vector_type(4)));
typedef unsigned short u16x8 __attribute__((ext_vector_type(8)));
typedef unsigned short u16x4 __attribute__((ext_vector_type(4)));

__device__ __forceinline__ float b2f(unsigned short u) {
    return __uint_as_float(((unsigned)u) << 16);
}
__device__ __forceinline__ unsigned short f2b(float f) {
    unsigned x = __float_as_uint(f);
    return (unsigned short)((x + 0x7fffu + ((x >> 16) & 1u)) >> 16);
}
__device__ __forceinline__ float wredsum(float v) {
#pragma unroll
    for (int m = 1; m < 64; m <<= 1) v += __shfl_xor(v, m);
    return v;
}
__device__ __forceinline__ float grp4sum(float v) {
    v += __shfl_xor(v, 1);
    v += __shfl_xor(v, 2);
    return v;
}

typedef __attribute__((address_space(3))) unsigned int lds_u32;
typedef const __attribute__((address_space(1))) unsigned int glb_u32;
__device__ __forceinline__ void gload_lds16(const unsigned short* g, unsigned short* l) {
    __builtin_amdgcn_global_load_lds((glb_u32*)g, (lds_u32*)l, 16, 0, 0);
}

// ---------------- dtype probe: 1 = bf16 inputs, 0 = f32 inputs ----------------
__global__ __launch_bounds__(256) void probe_kernel(
    const unsigned short* __restrict__ x, int* __restrict__ flag)
{
    int t = threadIdx.x;
    int c = 0;
    for (int i = t; i < 1024; i += 256) {
        unsigned e = (x[i] >> 7) & 0xFFu;
        c += (e >= 110u && e <= 135u) ? 1 : 0;
    }
#pragma unroll
    for (int m = 1; m < 64; m <<= 1) c += __shfl_xor(c, m);
    __shared__ int acc[4];
    if ((t & 63) == 0) acc[t >> 6] = c;
    __syncthreads();
    if (t == 0) *flag = ((acc[0] + acc[1] + acc[2] + acc[3]) >= 896) ? 1 : 0;
}

// ---------------- convert all params to bf16 in ws (+ transposed dw weights) ----------------
__global__ __launch_bounds__(256) void cvt_params_kernel(
    const int* __restrict__ flagp,
    const void* p0, const void* p1, const void* p2, const void* p3, const void* p4,
    const void* p5, const void* p6, const void* p7, const void* p8, const void* p9,
    const void* p10, const void* p11, const void* p12, const void* p13, const void* p14,
    const void* p15, const void* p16, const void* p17, const void* p18, const void* p19,
    unsigned short* __restrict__ dst)
{
    bool isb = (*flagp != 0);
    long g = (long)blockIdx.x * 256 + threadIdx.x;
    long str = (long)gridDim.x * 256;
#define CVT(src, off, n)                                                        \
    for (long i = g; i < (long)(n); i += str)                                   \
        dst[(off) + i] = isb ? ((const unsigned short*)(src))[i]                \
                             : f2b(((const float*)(src))[i]);
    CVT(p0, 0, 256)          // n1g
    CVT(p1, 256, 256)        // n1b
    CVT(p2, 512, 65536)      // linw
    CVT(p3, 66048, 256)      // linb
    CVT(p4, 66304, 65536)    // repw
    CVT(p5, 131840, 256)     // repb
    CVT(p6, 132096, 256)     // ang
    CVT(p7, 132352, 256)     // anb
    CVT(p8, 132608, 256)     // g2
    CVT(p9, 132864, 256)     // b2v
    CVT(p10, 133120, 131072) // fc1w
    CVT(p11, 264192, 512)    // fc1b
    // dw weights stored TRANSPOSED at 264704: dwt[tap][c] = dww[c][tap]
    for (long i = g; i < 4608; i += str) {
        int tap = (int)(i >> 9), c = (int)(i & 511);
        dst[264704 + i] = isb ? ((const unsigned short*)p12)[c * 9 + tap]
                              : f2b(((const float*)p12)[c * 9 + tap]);
    }
    CVT(p13, 269312, 512)    // dwb
    CVT(p14, 269824, 512)    // fn1g
    CVT(p15, 270336, 512)    // fn1b
    CVT(p16, 270848, 131072) // fc2w
    CVT(p17, 401920, 256)    // fc2b
    CVT(p18, 402176, 256)    // fn3g
    CVT(p19, 402432, 256)    // fn3b
#undef CVT
}

// ---------------- fused LN1 + lin GEMM: 128x256 tile, 16 waves, 80 KB LDS (2 blocks/CU) --------
// out[t][o] = sum_k LN(x)[t][k] * linw[o][k] + linb[o], t in [0, 2*BTOK)
// Single-buffer B; per-step: compute -> barrier -> stage -> vmcnt(0) -> barrier.
__global__ __launch_bounds__(1024) void lnlin_kernel(
    const void* __restrict__ x1, const void* __restrict__ x2,
    const unsigned short* __restrict__ g, const unsigned short* __restrict__ bb,
    const unsigned short* __restrict__ Wt, const unsigned short* __restrict__ bias,
    unsigned short* __restrict__ out, const int* __restrict__ flagp, int nwg)
{
    __shared__ unsigned short Alds[8 * 4096];   // 64 KB: 8 K-panels of [128][32] (swizzled slots)
    __shared__ unsigned short SB[8192];         // 16 KB: B single buffer (256 x 32 per K-step)
    int t = threadIdx.x, l = t & 63, w = t >> 6;   // 16 waves
    int bid = blockIdx.x, cpx = nwg >> 3;
    int wg = (bid & 7) * cpx + (bid >> 3);
    long tm = (long)wg << 7;
    int wr = (w >> 2) << 5, wc = (w & 3) << 6;     // wave tile 32 x 64

    // B staging: thread t covers W-row t>>2 (0..255), 1 gload/thread/stage
    int q = (t & 3) ^ ((t >> 3) & 3);
    const unsigned short* gbp = Wt + (long)(t >> 2) * 256 + q * 8;
    auto stageB = [&](int koff) {
        gload_lds16(gbp + koff, &SB[w * 512]);
    };
    stageB(0);   // lands during the LN phase

    // ---- LN staging of A (coalesced): wave w rows w*8+i, lane l cols 4l..4l+3 ----
    bool isb = (*flagp != 0);
    const void* xsel = (tm < (long)BTOK) ? x1 : x2;
    long grbase = ((tm < (long)BTOK) ? tm : (tm - BTOK)) + (long)w * 8;
    u16x4 gv4 = *reinterpret_cast<const u16x4*>(g + l * 4);
    u16x4 bv4 = *reinterpret_cast<const u16x4*>(bb + l * 4);
    float gvf[4], bvf[4];
#pragma unroll
    for (int j = 0; j < 4; j++) { gvf[j] = b2f(gv4[j]); bvf[j] = b2f(bv4[j]); }
    int pan = l >> 3;                 // K-panel 0..7 (col 4l / 32)
    int gidx = (l >> 1) & 3;          // 16B granule within panel
    int half = l & 1;                 // which 8B half of the granule
    float xq[8][4];
#pragma unroll
    for (int i = 0; i < 8; i++) {
        long rr_ = grbase + i;
        if (isb) {
            u16x4 v = *reinterpret_cast<const u16x4*>(
                (const unsigned short*)xsel + rr_ * 256 + l * 4);
#pragma unroll
            for (int j = 0; j < 4; j++) xq[i][j] = b2f(v[j]);
        } else {
            f32x4 v = *reinterpret_cast<const f32x4*>((const float*)xsel + rr_ * 256 + l * 4);
#pragma unroll
            for (int j = 0; j < 4; j++) xq[i][j] = v[j];
        }
    }
#pragma unroll
    for (int i = 0; i < 8; i++) {
        int r = w * 8 + i;
        float s1 = xq[i][0] + xq[i][1] + xq[i][2] + xq[i][3];
        float s2 = xq[i][0] * xq[i][0] + xq[i][1] * xq[i][1]
                 + xq[i][2] * xq[i][2] + xq[i][3] * xq[i][3];
        s1 = wredsum(s1);
        s2 = wredsum(s2);
        float mean = s1 * (1.f / 256);
        float rs = rsqrtf(s2 * (1.f / 256) - mean * mean + 1e-5f);
        u16x4 o;
#pragma unroll
        for (int j = 0; j < 4; j++)
            o[j] = f2b((xq[i][j] - mean) * rs * gvf[j] + bvf[j]);
        int sq = gidx ^ ((r >> 1) & 3);
        *reinterpret_cast<u16x4*>(&Alds[pan * 4096 + r * 32 + sq * 8 + half * 4]) = o;
    }

    // fragment offsets (read slot (l>>4) ^ ((rr>>1)&3); row offsets are multiples of 16)
    int rr = l & 15;
    int sA = ((l >> 4) ^ ((rr >> 1) & 3)) << 3;
    int aoff[2], boff[4];
#pragma unroll
    for (int m = 0; m < 2; m++) aoff[m] = (wr + m * 16 + rr) * 32 + sA;
#pragma unroll
    for (int n = 0; n < 4; n++) boff[n] = (wc + n * 16 + rr) * 32 + sA;

    f32x4 acc[2][4];
#pragma unroll
    for (int m = 0; m < 2; m++)
#pragma unroll
        for (int n = 0; n < 4; n++) acc[m][n] = {0.f, 0.f, 0.f, 0.f};

    // publish A (lgkm) + B step 0 (vmcnt)
    asm volatile("s_waitcnt vmcnt(0) lgkmcnt(0)" ::: "memory");
    __builtin_amdgcn_s_barrier();
    asm volatile("" ::: "memory");

#pragma unroll
    for (int kt = 0; kt < 8; kt++) {
        bf16x8 af[2], bfr[4];
#pragma unroll
        for (int m = 0; m < 2; m++)
            af[m] = *reinterpret_cast<const bf16x8*>(&Alds[kt * 4096 + aoff[m]]);
#pragma unroll
        for (int n = 0; n < 4; n++)
            bfr[n] = *reinterpret_cast<const bf16x8*>(&SB[boff[n]]);
#pragma unroll
        for (int m = 0; m < 2; m++)
#pragma unroll
            for (int n = 0; n < 4; n++)
                acc[m][n] = __builtin_amdgcn_mfma_f32_16x16x32_bf16(af[m], bfr[n], acc[m][n], 0, 0, 0);
        if (kt + 1 < 8) {
            __builtin_amdgcn_s_barrier();             // all SB reads of step kt retired
            asm volatile("" ::: "memory");
            stageB((kt + 1) * 32);
            asm volatile("s_waitcnt vmcnt(0)" ::: "memory");
            __builtin_amdgcn_s_barrier();             // SB refilled
            asm volatile("" ::: "memory");
        }
    }

    int orow = (l >> 4) << 2;
    int ocol = l & 15;
    float bi[4];
#pragma unroll
    for (int n = 0; n < 4; n++) bi[n] = b2f(bias[wc + n * 16 + ocol]);
#pragma unroll
    for (int m = 0; m < 2; m++) {
#pragma unroll
        for (int n = 0; n < 4; n++) {
#pragma unroll
            for (int j = 0; j < 4; j++) {
                out[(tm + wr + m * 16 + orow + j) * 256 + wc + n * 16 + ocol] =
                    f2b(acc[m][n][j] + bi[n]);
            }
        }
    }
}

// ---------------- GEMM: 128x128 tile, BK=32, 3-buffer counted-vmcnt pipeline ----------------
template<int K>
__global__ __launch_bounds__(256) void gemm_lds_kernel(
    const unsigned short* __restrict__ A, const unsigned short* __restrict__ Wt,
    const unsigned short* __restrict__ bias, unsigned short* __restrict__ out,
    int O, int nwg)
{
    __shared__ unsigned short Asm[3][4096];
    __shared__ unsigned short Bsm[3][4096];
    int t = threadIdx.x, l = t & 63, w = t >> 6;
    int bid = blockIdx.x, cpx = nwg >> 3;
    int wg = (bid & 7) * cpx + (bid >> 3);
    int ntn = O >> 7;
    long tm = (long)(wg / ntn) << 7;
    int tn = (wg % ntn) << 7;
    int wr = (w >> 1) << 6, wc = (w & 1) << 6;

    int rloc = t >> 2;
    int q = (t & 3) ^ ((t >> 3) & 3);
    const unsigned short* ga0 = A + (tm + rloc) * K + q * 8;
    const unsigned short* ga1 = ga0 + (long)64 * K;
    const unsigned short* gb0 = Wt + (long)(tn + rloc) * K + q * 8;
    const unsigned short* gb1 = gb0 + (long)64 * K;

    int rr = l & 15;
    int sA = ((l >> 4) ^ ((rr >> 1) & 3)) << 3;
    int aoff[4], boff[4];
#pragma unroll
    for (int m = 0; m < 4; m++) aoff[m] = (wr + m * 16 + rr) * 32 + sA;
#pragma unroll
    for (int n = 0; n < 4; n++) boff[n] = (wc + n * 16 + rr) * 32 + sA;

    f32x4 acc[4][4];
#pragma unroll
    for (int m = 0; m < 4; m++)
#pragma unroll
        for (int n = 0; n < 4; n++) acc[m][n] = {0.f, 0.f, 0.f, 0.f};

    auto stage = [&](int buf, int koff) {
        gload_lds16(ga0 + koff, &Asm[buf][w * 512]);
        gload_lds16(ga1 + koff, &Asm[buf][2048 + w * 512]);
        gload_lds16(gb0 + koff, &Bsm[buf][w * 512]);
        gload_lds16(gb1 + koff, &Bsm[buf][2048 + w * 512]);
    };
    auto compute = [&](int buf) {
        bf16x8 af[4], bfr[4];
#pragma unroll
        for (int m = 0; m < 4; m++) af[m] = *reinterpret_cast<const bf16x8*>(&Asm[buf][aoff[m]]);
#pragma unroll
        for (int n = 0; n < 4; n++) bfr[n] = *reinterpret_cast<const bf16x8*>(&Bsm[buf][boff[n]]);
#pragma unroll
        for (int m = 0; m < 4; m++)
#pragma unroll
            for (int n = 0; n < 4; n++)
                acc[m][n] = __builtin_amdgcn_mfma_f32_16x16x32_bf16(af[m], bfr[n], acc[m][n], 0, 0, 0);
    };

    constexpr int NK = K / 32;
    stage(0, 0);
    stage(1, 32);
    asm volatile("s_waitcnt vmcnt(4)" ::: "memory");
    __builtin_amdgcn_s_barrier();
    asm volatile("" ::: "memory");
#pragma unroll
    for (int kt = 0; kt < NK; kt++) {
        if (kt + 2 < NK) stage((kt + 2) % 3, (kt + 2) * 32);
        compute(kt % 3);
        if (kt + 1 < NK) {
            if (kt + 2 < NK) asm volatile("s_waitcnt vmcnt(4)" ::: "memory");
            else             asm volatile("s_waitcnt vmcnt(0)" ::: "memory");
            __builtin_amdgcn_s_barrier();
            asm volatile("" ::: "memory");
        }
    }

    int orow = (l >> 4) << 2;
    int ocol = l & 15;
    float bi[4];
#pragma unroll
    for (int n = 0; n < 4; n++) bi[n] = b2f(bias[tn + wc + n * 16 + ocol]);
#pragma unroll
    for (int m = 0; m < 4; m++) {
#pragma unroll
        for (int n = 0; n < 4; n++) {
#pragma unroll
            for (int j = 0; j < 4; j++) {
                out[(tm + wr + m * 16 + orow + j) * O + tn + wc + n * 16 + ocol] =
                    f2b(acc[m][n][j] + bi[n]);
            }
        }
    }
}

// ---------------- fused GEMM (O=256) + LN epilogue; 3-buffer counted-vmcnt, raw barriers --------
#define REPS 272
template<int K, int MODE>
__global__ __launch_bounds__(512) void gemm_fused_kernel(
    const unsigned short* __restrict__ A, const unsigned short* __restrict__ Wt,
    const unsigned short* __restrict__ bias, const void* __restrict__ xin,
    const unsigned short* __restrict__ g1, const unsigned short* __restrict__ b1,
    const unsigned short* __restrict__ g2p, const unsigned short* __restrict__ b2p,
    void* __restrict__ outp, const int* __restrict__ flagp, int nwg)
{
    __shared__ unsigned short SA[3][4096];
    __shared__ unsigned short SB[3][8192];
    __shared__ unsigned short Rep[128 * REPS];
    int t = threadIdx.x, l = t & 63, w = t >> 6;
    int bid = blockIdx.x, cpx = nwg >> 3;
    int wg = (bid & 7) * cpx + (bid >> 3);
    long tm = (long)wg << 7;
    int wr = (w >> 2) << 6, wc = (w & 3) << 6;

    int rloc = t >> 2;
    int q = (t & 3) ^ ((t >> 3) & 3);
    const unsigned short* ga0 = A + (tm + rloc) * K + q * 8;
    const unsigned short* gb0 = Wt + (long)rloc * K + q * 8;
    const unsigned short* gb1 = gb0 + (long)128 * K;

    int rr = l & 15;
    int sA = ((l >> 4) ^ ((rr >> 1) & 3)) << 3;
    int aoff[4], boff[4];
#pragma unroll
    for (int m = 0; m < 4; m++) aoff[m] = (wr + m * 16 + rr) * 32 + sA;
#pragma unroll
    for (int n = 0; n < 4; n++) boff[n] = (wc + n * 16 + rr) * 32 + sA;

    f32x4 acc[4][4];
#pragma unroll
    for (int m = 0; m < 4; m++)
#pragma unroll
        for (int n = 0; n < 4; n++) acc[m][n] = {0.f, 0.f, 0.f, 0.f};

    auto stage = [&](int buf, int koff) {
        gload_lds16(ga0 + koff, &SA[buf][w * 512]);
        gload_lds16(gb0 + koff, &SB[buf][w * 512]);
        gload_lds16(gb1 + koff, &SB[buf][4096 + w * 512]);
    };
    auto compute = [&](int buf) {
        bf16x8 af[4], bfr[4];
#pragma unroll
        for (int m = 0; m < 4; m++) af[m] = *reinterpret_cast<const bf16x8*>(&SA[buf][aoff[m]]);
#pragma unroll
        for (int n = 0; n < 4; n++) bfr[n] = *reinterpret_cast<const bf16x8*>(&SB[buf][boff[n]]);
#pragma unroll
        for (int m = 0; m < 4; m++)
#pragma unroll
            for (int n = 0; n < 4; n++)
                acc[m][n] = __builtin_amdgcn_mfma_f32_16x16x32_bf16(af[m], bfr[n], acc[m][n], 0, 0, 0);
    };

    constexpr int NK = K / 32;
    stage(0, 0);
    stage(1, 32);
    asm volatile("s_waitcnt vmcnt(3)" ::: "memory");
    __builtin_amdgcn_s_barrier();
    asm volatile("" ::: "memory");
#pragma unroll
    for (int kt = 0; kt < NK; kt++) {
        if (kt + 2 < NK) stage((kt + 2) % 3, (kt + 2) * 32);
        compute(kt % 3);
        if (kt + 1 < NK) {
            if (kt + 2 < NK) asm volatile("s_waitcnt vmcnt(3)" ::: "memory");
            else             asm volatile("s_waitcnt vmcnt(0)" ::: "memory");
            __builtin_amdgcn_s_barrier();
            asm volatile("" ::: "memory");
        }
    }

    // stage acc (+bias) to Rep (bf16) with padded stride
    int orow = (l >> 4) << 2, ocol = l & 15;
#pragma unroll
    for (int n = 0; n < 4; n++) {
        float bi = b2f(bias[wc + n * 16 + ocol]);
#pragma unroll
        for (int m = 0; m < 4; m++)
#pragma unroll
            for (int j = 0; j < 4; j++)
                Rep[(wr + m * 16 + orow + j) * REPS + wc + n * 16 + ocol] =
                    f2b(acc[m][n][j] + bi);
    }
    __syncthreads();

    // epilogue: thread t owns row r = t>>2, column chunks col = (t&3)*8 + i*32
    bool isb = (*flagp != 0);
    int r = t >> 2, qd = t & 3;
    long grow = tm + r;
    const unsigned short* rrow = Rep + r * REPS + qd * 8;
    u16x8 rv[8];
#pragma unroll
    for (int i = 0; i < 8; i++) rv[i] = *reinterpret_cast<const u16x8*>(rrow + i * 32);

    if constexpr (MODE == 0) {
        float s1 = 0.f;
#pragma unroll
        for (int i = 0; i < 8; i++)
#pragma unroll
            for (int j = 0; j < 8; j++) s1 += b2f(rv[i][j]);
        s1 = grp4sum(s1);
        float mean = s1 * (1.f / 256);
        float s2 = 0.f;
#pragma unroll
        for (int i = 0; i < 8; i++)
#pragma unroll
            for (int j = 0; j < 8; j++) { float d = b2f(rv[i][j]) - mean; s2 += d * d; }
        s2 = grp4sum(s2);
        float rs = rsqrtf(s2 * (1.f / 256) + 1e-5f);
        const float* xf = (const float*)xin + grow * 256 + qd * 8;
        const unsigned short* xb = (const unsigned short*)xin + grow * 256 + qd * 8;
        float tt[8][8];
        float t1 = 0.f, t2 = 0.f;
#pragma unroll
        for (int i = 0; i < 8; i++) {
            int cb = qd * 8 + i * 32;
            u16x8 gg = *reinterpret_cast<const u16x8*>(g1 + cb);
            u16x8 bb = *reinterpret_cast<const u16x8*>(b1 + cb);
            float xv[8];
            if (isb) {
                u16x8 x8 = *reinterpret_cast<const u16x8*>(xb + i * 32);
#pragma unroll
                for (int j = 0; j < 8; j++) xv[j] = b2f(x8[j]);
            } else {
                f32x4 a0 = *reinterpret_cast<const f32x4*>(xf + i * 32);
                f32x4 a1 = *reinterpret_cast<const f32x4*>(xf + i * 32 + 4);
#pragma unroll
                for (int j = 0; j < 4; j++) { xv[j] = a0[j]; xv[4 + j] = a1[j]; }
            }
#pragma unroll
            for (int j = 0; j < 8; j++) {
                float nv = (b2f(rv[i][j]) - mean) * rs * b2f(gg[j]) + b2f(bb[j]);
                float v = nv + xv[j];
                tt[i][j] = v;
                t1 += v; t2 += v * v;
            }
        }
        t1 = grp4sum(t1); t2 = grp4sum(t2);
        float mean2 = t1 * (1.f / 256);
        float rs2 = rsqrtf(t2 * (1.f / 256) - mean2 * mean2 + 1e-5f);
        unsigned short* ob = (unsigned short*)outp + grow * 256 + qd * 8;
#pragma unroll
        for (int i = 0; i < 8; i++) {
            int cb = qd * 8 + i * 32;
            u16x8 g2v = *reinterpret_cast<const u16x8*>(g2p + cb);
            u16x8 b2vv = *reinterpret_cast<const u16x8*>(b2p + cb);
            u16x8 o;
#pragma unroll
            for (int j = 0; j < 8; j++)
                o[j] = f2b((tt[i][j] - mean2) * rs2 * b2f(g2v[j]) + b2f(b2vv[j]));
            *reinterpret_cast<u16x8*>(ob + i * 32) = o;
        }
    } else {
        const unsigned short* yb = (const unsigned short*)xin + grow * 256 + qd * 8;
        u16x8 yv[8];
#pragma unroll
        for (int i = 0; i < 8; i++) yv[i] = *reinterpret_cast<const u16x8*>(yb + i * 32);
        float t1 = 0.f, t2 = 0.f;
#pragma unroll
        for (int i = 0; i < 8; i++)
#pragma unroll
            for (int j = 0; j < 8; j++) {
                float tt = b2f(rv[i][j]) + b2f(yv[i][j]);
                t1 += tt; t2 += tt * tt;
            }
        t1 = grp4sum(t1); t2 = grp4sum(t2);
        float mean2 = t1 * (1.f / 256);
        float rs2 = rsqrtf(t2 * (1.f / 256) - mean2 * mean2 + 1e-5f);
        float* of = (float*)outp + grow * 256 + qd * 8;
        unsigned short* ob = (unsigned short*)outp + grow * 256 + qd * 8;
#pragma unroll
        for (int i = 0; i < 8; i++) {
            int cb = qd * 8 + i * 32;
            u16x8 gg = *reinterpret_cast<const u16x8*>(g1 + cb);
            u16x8 bb = *reinterpret_cast<const u16x8*>(b1 + cb);
            float rvals[8];
#pragma unroll
            for (int j = 0; j < 8; j++) {
                float tt = b2f(rv[i][j]) + b2f(yv[i][j]);
                rvals[j] = (tt - mean2) * rs2 * b2f(gg[j]) + b2f(bb[j]);
            }
            if (isb) {
                u16x8 o;
#pragma unroll
                for (int j = 0; j < 8; j++) o[j] = f2b(rvals[j]);
                *reinterpret_cast<u16x8*>(ob + i * 32) = o;
            } else {
                f32x4 o0, o1;
#pragma unroll
                for (int j = 0; j < 4; j++) { o0[j] = rvals[j]; o1[j] = rvals[4 + j]; }
                *reinterpret_cast<f32x4*>(of + i * 32) = o0;
                *reinterpret_cast<f32x4*>(of + i * 32 + 4) = o1;
            }
        }
    }
}

// ---------------- ctx partial (no-max exp): slab of 256 tokens per block ----------------
__global__ __launch_bounds__(256) void ctx_part_kernel(
    const unsigned short* __restrict__ n2, float* __restrict__ pctx,
    float* __restrict__ pcs)
{
    int blk = blockIdx.x;
    int b = blk >> 7, hd = (blk >> 4) & 7, slab = blk & 15;
    int t = threadIdx.x;
    __shared__ float ld[32][33], eld[32][33];
    int d = t >> 3;
    int v0 = (t & 7) << 2;
    int ln_ = t >> 3;
    int lc = (t & 7) << 2;
    f32x4 acc = {0.f, 0.f, 0.f, 0.f};
    float se = 0.f;
    const unsigned short* base = n2 + ((long)b * 4096 + slab * 256) * CC + hd * 32;
    for (int n0 = 0; n0 < 256; n0 += 32) {
        u16x4 rv = *reinterpret_cast<const u16x4*>(base + (long)(n0 + ln_) * CC + lc);
#pragma unroll
        for (int j = 0; j < 4; j++) {
            float x = b2f(rv[j]);
            ld[ln_][lc + j] = x;
            eld[ln_][lc + j] = __expf(x);
        }
        __syncthreads();
#pragma unroll 4
        for (int nn = 0; nn < 32; nn++) {
            float e = eld[nn][d];
            se += e;
#pragma unroll
            for (int j = 0; j < 4; j++) acc[j] += e * ld[nn][v0 + j];
        }
        __syncthreads();
    }
    long o = ((long)slab * NBATCH * 8 + (long)b * 8 + hd) * 1024 + (long)d * 32 + v0;
#pragma unroll
    for (int j = 0; j < 4; j++) pctx[o + j] = acc[j];
    if ((t & 7) == 0)
        pcs[(long)slab * (NBATCH * 8 * 32) + ((long)(b * 8 + hd) << 5) + d] = se;
}

// ---------------- ctx reduce: sum 16 slab partials, normalize by column sum ----------------
__global__ __launch_bounds__(256) void ctx_reduce_kernel(
    const float* __restrict__ pctx, const float* __restrict__ pcs,
    float* __restrict__ ctx)
{
    long i = (long)blockIdx.x * 256 + threadIdx.x;   // 65536 elems
    int bh = (int)(i >> 10);
    int d = (int)((i >> 5) & 31);
    float s = 0.f, ps = 0.f;
#pragma unroll
    for (int sl = 0; sl < 16; sl++) {
        s += pctx[(long)sl * 65536 + i];
        ps += pcs[(long)sl * (NBATCH * 8 * 32) + (bh << 5) + d];
    }
    ctx[i] = s / ps;
}

// ---------------- q-softmax + att = ctx^T q, barrier-free shuffle version ----------------
__global__ __launch_bounds__(256) void att_kernel(
    const unsigned short* __restrict__ n1, const float* __restrict__ ctx,
    unsigned short* __restrict__ attv)
{
    __shared__ float cl[32 * 256];   // [d][c]
    int b = blockIdx.x >> 6, grp = blockIdx.x & 63;
    int t = threadIdx.x, wid = t >> 6, l = t & 63;
    const float* cb = ctx + (long)b * 8192;
    for (int i = 0; i < 32; i++) {
        int gidx = t + (i << 8);
        int hd_ = gidx >> 10, dd = (gidx >> 5) & 31, vv = gidx & 31;
        cl[dd * 256 + hd_ * 32 + vv] = cb[gidx];
    }
    __syncthreads();
    int base_lane = l & 56;
    long tokbase = (long)b * 4096 + grp * 64 + wid * 16;
    const f32x4* c4 = reinterpret_cast<const f32x4*>(cl);
    for (int it = 0; it < 16; it++) {
        long tok = tokbase + it;
        u16x4 rv = *reinterpret_cast<const u16x4*>(n1 + tok * CC + l * 4);
        float x[4];
#pragma unroll
        for (int j = 0; j < 4; j++) x[j] = b2f(rv[j]);
        float mx = fmaxf(fmaxf(x[0], x[1]), fmaxf(x[2], x[3]));
        mx = fmaxf(mx, __shfl_xor(mx, 1));
        mx = fmaxf(mx, __shfl_xor(mx, 2));
        mx = fmaxf(mx, __shfl_xor(mx, 4));
        float e[4], s = 0.f;
#pragma unroll
        for (int j = 0; j < 4; j++) { e[j] = __expf(x[j] - mx); s += e[j]; }
        s += __shfl_xor(s, 1);
        s += __shfl_xor(s, 2);
        s += __shfl_xor(s, 4);
        float inv = 1.f / s;
        f32x4 o = {0.f, 0.f, 0.f, 0.f};
#pragma unroll
        for (int dd = 0; dd < 32; dd++) {
            float qv = __shfl(e[dd & 3], base_lane + (dd >> 2));
            o += qv * c4[dd * 64 + l];
        }
        o *= inv;
        u16x4 ov;
#pragma unroll
        for (int j = 0; j < 4; j++) ov[j] = f2b(o[j]);
        *reinterpret_cast<u16x4*>(attv + tok * CC + l * 4) = ov;
    }
}

// ---------------- depthwise 3x3 conv + LN + tanh-GELU (transposed weights, XCD swizzle) -------
__global__ __launch_bounds__(256) void dw_kernel(
    const unsigned short* __restrict__ h1, const unsigned short* __restrict__ dwt,
    const unsigned short* __restrict__ dwb, const unsigned short* __restrict__ g,
    const unsigned short* __restrict__ bb, unsigned short* __restrict__ ax, int nwg)
{
    int wid = threadIdx.x >> 6, l = threadIdx.x & 63;
    int bid = blockIdx.x, cpx = nwg >> 3;
    int wg = (bid & 7) * cpx + (bid >> 3);      // bijective XCD swizzle (nwg % 8 == 0)
    int pix = wg * 4 + wid;
    int b = pix >> 12, rem = pix & 4095, py = rem >> 6, px = rem & 63;
    int c0 = l * 8;
    u16x8 wv[9];
#pragma unroll
    for (int tap = 0; tap < 9; tap++)
        wv[tap] = *reinterpret_cast<const u16x8*>(dwt + tap * CC2 + c0);
    u16x8 biasv = *reinterpret_cast<const u16x8*>(dwb + c0);
    float acc[8];
#pragma unroll
    for (int j = 0; j < 8; j++) acc[j] = b2f(biasv[j]);
#pragma unroll
    for (int ky = 0; ky < 3; ky++) {
        int ys = py + ky - 1;
        if ((unsigned)ys >= 64u) continue;
#pragma unroll
        for (int kx = 0; kx < 3; kx++) {
            int xs = px + kx - 1;
            if ((unsigned)xs >= 64u) continue;
            u16x8 pv = *reinterpret_cast<const u16x8*>(
                h1 + ((long)(b << 12) + (ys << 6) + xs) * CC2 + c0);
            int tap = ky * 3 + kx;
#pragma unroll
            for (int j = 0; j < 8; j++)
                acc[j] += b2f(pv[j]) * b2f(wv[tap][j]);
        }
    }
    float s = 0.f;
#pragma unroll
    for (int j = 0; j < 8; j++) s += acc[j];
    float mean = wredsum(s) * (1.f / CC2);
    float d[8], sq = 0.f;
#pragma unroll
    for (int j = 0; j < 8; j++) { d[j] = acc[j] - mean; sq += d[j] * d[j]; }
    float rs = rsqrtf(wredsum(sq) * (1.f / CC2) + 1e-5f);
    u16x8 gv = *reinterpret_cast<const u16x8*>(g + c0);
    u16x8 bv = *reinterpret_cast<const u16x8*>(bb + c0);
    u16x8 o;
#pragma unroll
    for (int j = 0; j < 8; j++) {
        float nv = d[j] * rs * b2f(gv[j]) + b2f(bv[j]);
        float u = 1.59576912f * nv * (1.f + 0.044715f * nv * nv);
        float gl = nv / (1.f + __expf(-u));
        o[j] = f2b(gl);
    }
    *reinterpret_cast<u16x8*>(ax + (long)pix * CC2 + c0) = o;
}

extern "C" void kernel_launch(void* const* d_in, const int* in_sizes, int n_in,
                              void* d_out, int out_size, void* d_ws, size_t ws_size,
                              hipStream_t stream)
{
    char* w = (char*)d_ws;
    const size_t S1B = (size_t)BTOK * CC * 2;   // 16.78 MB
    const size_t STATSB = (size_t)(2 * NBATCH * CC + NBATCH * 8 * 32 * 32) * 4;
    const size_t PARAMS_ELEMS = 402688;
    const size_t need = 6 * S1B + STATSB + 64 + PARAMS_ELEMS * 2;
    if (ws_size < need) return;

    unsigned short* ln12 = (unsigned short*)w;
    unsigned short* n12  = (unsigned short*)(w + 2 * S1B);
    unsigned short* nn1  = n12;
    unsigned short* nn2  = n12 + (size_t)BTOK * CC;
    unsigned short* attv = ln12;
    unsigned short* ybuf = nn1;
    unsigned short* h1   = ln12;
    unsigned short* axb  = (unsigned short*)(w + 4 * S1B);
    float* pctx = (float*)(w + 4 * S1B + (2048 << 10));             // 4 MB
    float* pcs  = (float*)(w + 4 * S1B + (2048 << 10) + (4 << 20)); // 128 KB
    float* ctxb = (float*)(w + 6 * S1B) + 2 * NBATCH * CC;
    int*   flag = (int*)(w + 6 * S1B + STATSB);
    unsigned short* pb = (unsigned short*)(w + 6 * S1B + STATSB + 64);

    unsigned short* n1g  = pb + 0;
    unsigned short* n1b  = pb + 256;
    unsigned short* linw = pb + 512;
    unsigned short* linb = pb + 66048;
    unsigned short* repw = pb + 66304;
    unsigned short* repb = pb + 131840;
    unsigned short* ang  = pb + 132096;
    unsigned short* anb  = pb + 132352;
    unsigned short* g2   = pb + 132608;
    unsigned short* b2v  = pb + 132864;
    unsigned short* fc1w = pb + 133120;
    unsigned short* fc1b = pb + 264192;
    unsigned short* dwt  = pb + 264704;
    unsigned short* dwb  = pb + 269312;
    unsigned short* fn1g = pb + 269824;
    unsigned short* fn1b = pb + 270336;
    unsigned short* fc2w = pb + 270848;
    unsigned short* fc2b = pb + 401920;
    unsigned short* fn3g = pb + 402176;
    unsigned short* fn3b = pb + 402432;

    probe_kernel<<<1, 256, 0, stream>>>((const unsigned short*)d_in[0], flag);
    cvt_params_kernel<<<512, 256, 0, stream>>>(flag,
        d_in[2], d_in[3], d_in[4], d_in[5], d_in[6], d_in[7], d_in[8], d_in[9],
        d_in[10], d_in[11], d_in[12], d_in[13], d_in[14], d_in[15], d_in[16],
        d_in[17], d_in[18], d_in[19], d_in[20], d_in[21], pb);
    {   // fused LN1 + lin: T = 2*BTOK, O = 256
        int nwg = 2 * BTOK / 128;                  // 512
        lnlin_kernel<<<nwg, 1024, 0, stream>>>(
            d_in[0], d_in[1], n1g, n1b, linw, linb, n12, flag, nwg);
    }
    ctx_part_kernel<<<NBATCH * 8 * 16, 256, 0, stream>>>(nn2, pctx, pcs);
    ctx_reduce_kernel<<<256, 256, 0, stream>>>(pctx, pcs, ctxb);
    att_kernel<<<NBATCH * 64, 256, 0, stream>>>(nn1, ctxb, attv);
    {   // reproj + attnLN + x1 + LN2 -> ybuf
        int nwg = BTOK / 128;                      // 256
        gemm_fused_kernel<256, 0><<<nwg, 512, 0, stream>>>(
            attv, repw, repb, d_in[0], ang, anb, g2, b2v, ybuf, flag, nwg);
    }
    {   // fc1: T = BTOK, O = 512
        int nwg = (BTOK / 128) * (CC2 / 128);      // 1024
        gemm_lds_kernel<256><<<nwg, 256, 0, stream>>>(ybuf, fc1w, fc1b, h1, CC2, nwg);
    }
    dw_kernel<<<BTOK / 4, 256, 0, stream>>>(h1, dwt, dwb, fn1g, fn1b, axb, BTOK / 4);
    {   // fc2 + y + finalLN -> out
        int nwg = BTOK / 128;                      // 256
        gemm_fused_kernel<512, 1><<<nwg, 512, 0, stream>>>(
            axb, fc2w, fc2b, ybuf, fn3g, fn3b, fn3g, fn3b, d_out, flag, nwg);
    }
}

// Round 21
// 190.493 us; speedup vs baseline: 1.0092x; 1.0092x over previous
//
#include <hip/hip_runtime.h>

#define BTOK 32768   // B*H*W tokens
#define CC 256
#define CC2 512
#define NBATCH 8

typedef __bf16 bf16x8 __attribute__((ext_vector_type(8)));
typedef float f32x4 __attribute__((ext_vector_type(4)));
typedef unsigned short u16x8 __attribute__((ext_vector_type(8)));
typedef unsigned short u16x4 __attribute__((ext_vector_type(4)));

__device__ __forceinline__ float b2f(unsigned short u) {
    return __uint_as_float(((unsigned)u) << 16);
}
__device__ __forceinline__ unsigned short f2b(float f) {
    unsigned x = __float_as_uint(f);
    return (unsigned short)((x + 0x7fffu + ((x >> 16) & 1u)) >> 16);
}
__device__ __forceinline__ float wredsum(float v) {
#pragma unroll
    for (int m = 1; m < 64; m <<= 1) v += __shfl_xor(v, m);
    return v;
}
__device__ __forceinline__ float grp4sum(float v) {
    v += __shfl_xor(v, 1);
    v += __shfl_xor(v, 2);
    return v;
}

typedef __attribute__((address_space(3))) unsigned int lds_u32;
typedef const __attribute__((address_space(1))) unsigned int glb_u32;
__device__ __forceinline__ void gload_lds16(const unsigned short* g, unsigned short* l) {
    __builtin_amdgcn_global_load_lds((glb_u32*)g, (lds_u32*)l, 16, 0, 0);
}

// ---------------- dtype probe: 1 = bf16 inputs, 0 = f32 inputs ----------------
__global__ __launch_bounds__(256) void probe_kernel(
    const unsigned short* __restrict__ x, int* __restrict__ flag)
{
    int t = threadIdx.x;
    int c = 0;
    for (int i = t; i < 1024; i += 256) {
        unsigned e = (x[i] >> 7) & 0xFFu;
        c += (e >= 110u && e <= 135u) ? 1 : 0;
    }
#pragma unroll
    for (int m = 1; m < 64; m <<= 1) c += __shfl_xor(c, m);
    __shared__ int acc[4];
    if ((t & 63) == 0) acc[t >> 6] = c;
    __syncthreads();
    if (t == 0) *flag = ((acc[0] + acc[1] + acc[2] + acc[3]) >= 896) ? 1 : 0;
}

// ---------------- convert all params to bf16 in ws (+ transposed dw weights) ----------------
__global__ __launch_bounds__(256) void cvt_params_kernel(
    const int* __restrict__ flagp,
    const void* p0, const void* p1, const void* p2, const void* p3, const void* p4,
    const void* p5, const void* p6, const void* p7, const void* p8, const void* p9,
    const void* p10, const void* p11, const void* p12, const void* p13, const void* p14,
    const void* p15, const void* p16, const void* p17, const void* p18, const void* p19,
    unsigned short* __restrict__ dst)
{
    bool isb = (*flagp != 0);
    long g = (long)blockIdx.x * 256 + threadIdx.x;
    long str = (long)gridDim.x * 256;
#define CVT(src, off, n)                                                        \
    for (long i = g; i < (long)(n); i += str)                                   \
        dst[(off) + i] = isb ? ((const unsigned short*)(src))[i]                \
                             : f2b(((const float*)(src))[i]);
    CVT(p0, 0, 256)          // n1g
    CVT(p1, 256, 256)        // n1b
    CVT(p2, 512, 65536)      // linw
    CVT(p3, 66048, 256)      // linb
    CVT(p4, 66304, 65536)    // repw
    CVT(p5, 131840, 256)     // repb
    CVT(p6, 132096, 256)     // ang
    CVT(p7, 132352, 256)     // anb
    CVT(p8, 132608, 256)     // g2
    CVT(p9, 132864, 256)     // b2v
    CVT(p10, 133120, 131072) // fc1w
    CVT(p11, 264192, 512)    // fc1b
    // dw weights stored TRANSPOSED at 264704: dwt[tap][c] = dww[c][tap]
    for (long i = g; i < 4608; i += str) {
        int tap = (int)(i >> 9), c = (int)(i & 511);
        dst[264704 + i] = isb ? ((const unsigned short*)p12)[c * 9 + tap]
                              : f2b(((const float*)p12)[c * 9 + tap]);
    }
    CVT(p13, 269312, 512)    // dwb
    CVT(p14, 269824, 512)    // fn1g
    CVT(p15, 270336, 512)    // fn1b
    CVT(p16, 270848, 131072) // fc2w
    CVT(p17, 401920, 256)    // fc2b
    CVT(p18, 402176, 256)    // fn3g
    CVT(p19, 402432, 256)    // fn3b
#undef CVT
}

// ---------------- fused LN1 + lin GEMM: 128x256 tile, 16 waves, A resident in LDS ----------------
__global__ __launch_bounds__(1024) void lnlin_kernel(
    const void* __restrict__ x1, const void* __restrict__ x2,
    const unsigned short* __restrict__ g, const unsigned short* __restrict__ bb,
    const unsigned short* __restrict__ Wt, const unsigned short* __restrict__ bias,
    unsigned short* __restrict__ out, const int* __restrict__ flagp, int nwg)
{
    __shared__ unsigned short Alds[8 * 4096];   // 64 KB: 8 K-panels of [128][32] (swizzled slots)
    __shared__ unsigned short SB[3][8192];      // 48 KB: B 3-buffer (256 x 32 per K-step)
    int t = threadIdx.x, l = t & 63, w = t >> 6;   // 16 waves
    int bid = blockIdx.x, cpx = nwg >> 3;
    int wg = (bid & 7) * cpx + (bid >> 3);
    long tm = (long)wg << 7;
    int wr = (w >> 2) << 5, wc = (w & 3) << 6;     // wave tile 32 x 64

    // B staging: thread t covers W-row t>>2 (0..255), 1 gload/thread/stage
    int q = (t & 3) ^ ((t >> 3) & 3);
    const unsigned short* gbp = Wt + (long)(t >> 2) * 256 + q * 8;
    auto stageB = [&](int buf, int koff) {
        gload_lds16(gbp + koff, &SB[buf][w * 512]);
    };
    stageB(0, 0);
    stageB(1, 32);

    // ---- LN staging of A (coalesced): wave w rows w*8+i, lane l cols 4l..4l+3 ----
    bool isb = (*flagp != 0);
    const void* xsel = (tm < (long)BTOK) ? x1 : x2;
    long grbase = ((tm < (long)BTOK) ? tm : (tm - BTOK)) + (long)w * 8;
    u16x4 gv4 = *reinterpret_cast<const u16x4*>(g + l * 4);
    u16x4 bv4 = *reinterpret_cast<const u16x4*>(bb + l * 4);
    float gvf[4], bvf[4];
#pragma unroll
    for (int j = 0; j < 4; j++) { gvf[j] = b2f(gv4[j]); bvf[j] = b2f(bv4[j]); }
    int pan = l >> 3;                 // K-panel 0..7 (col 4l / 32)
    int gidx = (l >> 1) & 3;          // 16B granule within panel
    int half = l & 1;                 // which 8B half of the granule
    float xq[8][4];
#pragma unroll
    for (int i = 0; i < 8; i++) {
        long rr_ = grbase + i;
        if (isb) {
            u16x4 v = *reinterpret_cast<const u16x4*>(
                (const unsigned short*)xsel + rr_ * 256 + l * 4);
#pragma unroll
            for (int j = 0; j < 4; j++) xq[i][j] = b2f(v[j]);
        } else {
            f32x4 v = *reinterpret_cast<const f32x4*>((const float*)xsel + rr_ * 256 + l * 4);
#pragma unroll
            for (int j = 0; j < 4; j++) xq[i][j] = v[j];
        }
    }
#pragma unroll
    for (int i = 0; i < 8; i++) {
        int r = w * 8 + i;
        float s1 = xq[i][0] + xq[i][1] + xq[i][2] + xq[i][3];
        float s2 = xq[i][0] * xq[i][0] + xq[i][1] * xq[i][1]
                 + xq[i][2] * xq[i][2] + xq[i][3] * xq[i][3];
        s1 = wredsum(s1);
        s2 = wredsum(s2);
        float mean = s1 * (1.f / 256);
        float rs = rsqrtf(s2 * (1.f / 256) - mean * mean + 1e-5f);
        u16x4 o;
#pragma unroll
        for (int j = 0; j < 4; j++)
            o[j] = f2b((xq[i][j] - mean) * rs * gvf[j] + bvf[j]);
        int sq = gidx ^ ((r >> 1) & 3);
        *reinterpret_cast<u16x4*>(&Alds[pan * 4096 + r * 32 + sq * 8 + half * 4]) = o;
    }

    // fragment offsets (read slot (l>>4) ^ ((rr>>1)&3); row offsets are multiples of 16)
    int rr = l & 15;
    int sA = ((l >> 4) ^ ((rr >> 1) & 3)) << 3;
    int aoff[2], boff[4];
#pragma unroll
    for (int m = 0; m < 2; m++) aoff[m] = (wr + m * 16 + rr) * 32 + sA;
#pragma unroll
    for (int n = 0; n < 4; n++) boff[n] = (wc + n * 16 + rr) * 32 + sA;

    f32x4 acc[2][4];
#pragma unroll
    for (int m = 0; m < 2; m++)
#pragma unroll
        for (int n = 0; n < 4; n++) acc[m][n] = {0.f, 0.f, 0.f, 0.f};

    // publish A (lgkm) + B buf0 (vmcnt(1): buf1's load may stay in flight)
    asm volatile("s_waitcnt vmcnt(1) lgkmcnt(0)" ::: "memory");
    __builtin_amdgcn_s_barrier();
    asm volatile("" ::: "memory");

#pragma unroll
    for (int kt = 0; kt < 8; kt++) {
        if (kt + 2 < 8) stageB((kt + 2) % 3, (kt + 2) * 32);
        bf16x8 af[2], bfr[4];
#pragma unroll
        for (int m = 0; m < 2; m++)
            af[m] = *reinterpret_cast<const bf16x8*>(&Alds[kt * 4096 + aoff[m]]);
#pragma unroll
        for (int n = 0; n < 4; n++)
            bfr[n] = *reinterpret_cast<const bf16x8*>(&SB[kt % 3][boff[n]]);
#pragma unroll
        for (int m = 0; m < 2; m++)
#pragma unroll
            for (int n = 0; n < 4; n++)
                acc[m][n] = __builtin_amdgcn_mfma_f32_16x16x32_bf16(af[m], bfr[n], acc[m][n], 0, 0, 0);
        if (kt + 1 < 8) {
            if (kt + 2 < 8) asm volatile("s_waitcnt vmcnt(1)" ::: "memory");
            else            asm volatile("s_waitcnt vmcnt(0)" ::: "memory");
            __builtin_amdgcn_s_barrier();
            asm volatile("" ::: "memory");
        }
    }

    int orow = (l >> 4) << 2;
    int ocol = l & 15;
    float bi[4];
#pragma unroll
    for (int n = 0; n < 4; n++) bi[n] = b2f(bias[wc + n * 16 + ocol]);
#pragma unroll
    for (int m = 0; m < 2; m++) {
#pragma unroll
        for (int n = 0; n < 4; n++) {
#pragma unroll
            for (int j = 0; j < 4; j++) {
                out[(tm + wr + m * 16 + orow + j) * 256 + wc + n * 16 + ocol] =
                    f2b(acc[m][n][j] + bi[n]);
            }
        }
    }
}

// ---------------- GEMM: 128x128 tile, BK=32, 3-buffer counted-vmcnt pipeline ----------------
template<int K>
__global__ __launch_bounds__(256) void gemm_lds_kernel(
    const unsigned short* __restrict__ A, const unsigned short* __restrict__ Wt,
    const unsigned short* __restrict__ bias, unsigned short* __restrict__ out,
    int O, int nwg)
{
    __shared__ unsigned short Asm[3][4096];
    __shared__ unsigned short Bsm[3][4096];
    int t = threadIdx.x, l = t & 63, w = t >> 6;
    int bid = blockIdx.x, cpx = nwg >> 3;
    int wg = (bid & 7) * cpx + (bid >> 3);
    int ntn = O >> 7;
    long tm = (long)(wg / ntn) << 7;
    int tn = (wg % ntn) << 7;
    int wr = (w >> 1) << 6, wc = (w & 1) << 6;

    int rloc = t >> 2;
    int q = (t & 3) ^ ((t >> 3) & 3);
    const unsigned short* ga0 = A + (tm + rloc) * K + q * 8;
    const unsigned short* ga1 = ga0 + (long)64 * K;
    const unsigned short* gb0 = Wt + (long)(tn + rloc) * K + q * 8;
    const unsigned short* gb1 = gb0 + (long)64 * K;

    int rr = l & 15;
    int sA = ((l >> 4) ^ ((rr >> 1) & 3)) << 3;
    int aoff[4], boff[4];
#pragma unroll
    for (int m = 0; m < 4; m++) aoff[m] = (wr + m * 16 + rr) * 32 + sA;
#pragma unroll
    for (int n = 0; n < 4; n++) boff[n] = (wc + n * 16 + rr) * 32 + sA;

    f32x4 acc[4][4];
#pragma unroll
    for (int m = 0; m < 4; m++)
#pragma unroll
        for (int n = 0; n < 4; n++) acc[m][n] = {0.f, 0.f, 0.f, 0.f};

    auto stage = [&](int buf, int koff) {
        gload_lds16(ga0 + koff, &Asm[buf][w * 512]);
        gload_lds16(ga1 + koff, &Asm[buf][2048 + w * 512]);
        gload_lds16(gb0 + koff, &Bsm[buf][w * 512]);
        gload_lds16(gb1 + koff, &Bsm[buf][2048 + w * 512]);
    };
    auto compute = [&](int buf) {
        bf16x8 af[4], bfr[4];
#pragma unroll
        for (int m = 0; m < 4; m++) af[m] = *reinterpret_cast<const bf16x8*>(&Asm[buf][aoff[m]]);
#pragma unroll
        for (int n = 0; n < 4; n++) bfr[n] = *reinterpret_cast<const bf16x8*>(&Bsm[buf][boff[n]]);
#pragma unroll
        for (int m = 0; m < 4; m++)
#pragma unroll
            for (int n = 0; n < 4; n++)
                acc[m][n] = __builtin_amdgcn_mfma_f32_16x16x32_bf16(af[m], bfr[n], acc[m][n], 0, 0, 0);
    };

    constexpr int NK = K / 32;
    stage(0, 0);
    stage(1, 32);
    asm volatile("s_waitcnt vmcnt(4)" ::: "memory");
    __builtin_amdgcn_s_barrier();
    asm volatile("" ::: "memory");
#pragma unroll
    for (int kt = 0; kt < NK; kt++) {
        if (kt + 2 < NK) stage((kt + 2) % 3, (kt + 2) * 32);
        compute(kt % 3);
        if (kt + 1 < NK) {
            if (kt + 2 < NK) asm volatile("s_waitcnt vmcnt(4)" ::: "memory");
            else             asm volatile("s_waitcnt vmcnt(0)" ::: "memory");
            __builtin_amdgcn_s_barrier();
            asm volatile("" ::: "memory");
        }
    }

    int orow = (l >> 4) << 2;
    int ocol = l & 15;
    float bi[4];
#pragma unroll
    for (int n = 0; n < 4; n++) bi[n] = b2f(bias[tn + wc + n * 16 + ocol]);
#pragma unroll
    for (int m = 0; m < 4; m++) {
#pragma unroll
        for (int n = 0; n < 4; n++) {
#pragma unroll
            for (int j = 0; j < 4; j++) {
                out[(tm + wr + m * 16 + orow + j) * O + tn + wc + n * 16 + ocol] =
                    f2b(acc[m][n][j] + bi[n]);
            }
        }
    }
}

// ---------------- fused GEMM (O=256) + LN epilogue; 3-buffer counted-vmcnt, raw barriers --------
#define REPS 272
template<int K, int MODE>
__global__ __launch_bounds__(512) void gemm_fused_kernel(
    const unsigned short* __restrict__ A, const unsigned short* __restrict__ Wt,
    const unsigned short* __restrict__ bias, const void* __restrict__ xin,
    const unsigned short* __restrict__ g1, const unsigned short* __restrict__ b1,
    const unsigned short* __restrict__ g2p, const unsigned short* __restrict__ b2p,
    void* __restrict__ outp, const int* __restrict__ flagp, int nwg)
{
    __shared__ unsigned short SA[3][4096];
    __shared__ unsigned short SB[3][8192];
    __shared__ unsigned short Rep[128 * REPS];
    int t = threadIdx.x, l = t & 63, w = t >> 6;
    int bid = blockIdx.x, cpx = nwg >> 3;
    int wg = (bid & 7) * cpx + (bid >> 3);
    long tm = (long)wg << 7;
    int wr = (w >> 2) << 6, wc = (w & 3) << 6;

    int rloc = t >> 2;
    int q = (t & 3) ^ ((t >> 3) & 3);
    const unsigned short* ga0 = A + (tm + rloc) * K + q * 8;
    const unsigned short* gb0 = Wt + (long)rloc * K + q * 8;
    const unsigned short* gb1 = gb0 + (long)128 * K;

    int rr = l & 15;
    int sA = ((l >> 4) ^ ((rr >> 1) & 3)) << 3;
    int aoff[4], boff[4];
#pragma unroll
    for (int m = 0; m < 4; m++) aoff[m] = (wr + m * 16 + rr) * 32 + sA;
#pragma unroll
    for (int n = 0; n < 4; n++) boff[n] = (wc + n * 16 + rr) * 32 + sA;

    f32x4 acc[4][4];
#pragma unroll
    for (int m = 0; m < 4; m++)
#pragma unroll
        for (int n = 0; n < 4; n++) acc[m][n] = {0.f, 0.f, 0.f, 0.f};

    auto stage = [&](int buf, int koff) {
        gload_lds16(ga0 + koff, &SA[buf][w * 512]);
        gload_lds16(gb0 + koff, &SB[buf][w * 512]);
        gload_lds16(gb1 + koff, &SB[buf][4096 + w * 512]);
    };
    auto compute = [&](int buf) {
        bf16x8 af[4], bfr[4];
#pragma unroll
        for (int m = 0; m < 4; m++) af[m] = *reinterpret_cast<const bf16x8*>(&SA[buf][aoff[m]]);
#pragma unroll
        for (int n = 0; n < 4; n++) bfr[n] = *reinterpret_cast<const bf16x8*>(&SB[buf][boff[n]]);
#pragma unroll
        for (int m = 0; m < 4; m++)
#pragma unroll
            for (int n = 0; n < 4; n++)
                acc[m][n] = __builtin_amdgcn_mfma_f32_16x16x32_bf16(af[m], bfr[n], acc[m][n], 0, 0, 0);
    };

    constexpr int NK = K / 32;
    stage(0, 0);
    stage(1, 32);
    asm volatile("s_waitcnt vmcnt(3)" ::: "memory");
    __builtin_amdgcn_s_barrier();
    asm volatile("" ::: "memory");
#pragma unroll
    for (int kt = 0; kt < NK; kt++) {
        if (kt + 2 < NK) stage((kt + 2) % 3, (kt + 2) * 32);
        compute(kt % 3);
        if (kt + 1 < NK) {
            if (kt + 2 < NK) asm volatile("s_waitcnt vmcnt(3)" ::: "memory");
            else             asm volatile("s_waitcnt vmcnt(0)" ::: "memory");
            __builtin_amdgcn_s_barrier();
            asm volatile("" ::: "memory");
        }
    }

    // stage acc (+bias) to Rep (bf16) with padded stride
    int orow = (l >> 4) << 2, ocol = l & 15;
#pragma unroll
    for (int n = 0; n < 4; n++) {
        float bi = b2f(bias[wc + n * 16 + ocol]);
#pragma unroll
        for (int m = 0; m < 4; m++)
#pragma unroll
            for (int j = 0; j < 4; j++)
                Rep[(wr + m * 16 + orow + j) * REPS + wc + n * 16 + ocol] =
                    f2b(acc[m][n][j] + bi);
    }
    __syncthreads();

    // epilogue: thread t owns row r = t>>2, column chunks col = (t&3)*8 + i*32
    bool isb = (*flagp != 0);
    int r = t >> 2, qd = t & 3;
    long grow = tm + r;
    const unsigned short* rrow = Rep + r * REPS + qd * 8;
    u16x8 rv[8];
#pragma unroll
    for (int i = 0; i < 8; i++) rv[i] = *reinterpret_cast<const u16x8*>(rrow + i * 32);

    if constexpr (MODE == 0) {
        float s1 = 0.f;
#pragma unroll
        for (int i = 0; i < 8; i++)
#pragma unroll
            for (int j = 0; j < 8; j++) s1 += b2f(rv[i][j]);
        s1 = grp4sum(s1);
        float mean = s1 * (1.f / 256);
        float s2 = 0.f;
#pragma unroll
        for (int i = 0; i < 8; i++)
#pragma unroll
            for (int j = 0; j < 8; j++) { float d = b2f(rv[i][j]) - mean; s2 += d * d; }
        s2 = grp4sum(s2);
        float rs = rsqrtf(s2 * (1.f / 256) + 1e-5f);
        const float* xf = (const float*)xin + grow * 256 + qd * 8;
        const unsigned short* xb = (const unsigned short*)xin + grow * 256 + qd * 8;
        float tt[8][8];
        float t1 = 0.f, t2 = 0.f;
#pragma unroll
        for (int i = 0; i < 8; i++) {
            int cb = qd * 8 + i * 32;
            u16x8 gg = *reinterpret_cast<const u16x8*>(g1 + cb);
            u16x8 bb = *reinterpret_cast<const u16x8*>(b1 + cb);
            float xv[8];
            if (isb) {
                u16x8 x8 = *reinterpret_cast<const u16x8*>(xb + i * 32);
#pragma unroll
                for (int j = 0; j < 8; j++) xv[j] = b2f(x8[j]);
            } else {
                f32x4 a0 = *reinterpret_cast<const f32x4*>(xf + i * 32);
                f32x4 a1 = *reinterpret_cast<const f32x4*>(xf + i * 32 + 4);
#pragma unroll
                for (int j = 0; j < 4; j++) { xv[j] = a0[j]; xv[4 + j] = a1[j]; }
            }
#pragma unroll
            for (int j = 0; j < 8; j++) {
                float nv = (b2f(rv[i][j]) - mean) * rs * b2f(gg[j]) + b2f(bb[j]);
                float v = nv + xv[j];
                tt[i][j] = v;
                t1 += v; t2 += v * v;
            }
        }
        t1 = grp4sum(t1); t2 = grp4sum(t2);
        float mean2 = t1 * (1.f / 256);
        float rs2 = rsqrtf(t2 * (1.f / 256) - mean2 * mean2 + 1e-5f);
        unsigned short* ob = (unsigned short*)outp + grow * 256 + qd * 8;
#pragma unroll
        for (int i = 0; i < 8; i++) {
            int cb = qd * 8 + i * 32;
            u16x8 g2v = *reinterpret_cast<const u16x8*>(g2p + cb);
            u16x8 b2vv = *reinterpret_cast<const u16x8*>(b2p + cb);
            u16x8 o;
#pragma unroll
            for (int j = 0; j < 8; j++)
                o[j] = f2b((tt[i][j] - mean2) * rs2 * b2f(g2v[j]) + b2f(b2vv[j]));
            *reinterpret_cast<u16x8*>(ob + i * 32) = o;
        }
    } else {
        const unsigned short* yb = (const unsigned short*)xin + grow * 256 + qd * 8;
        u16x8 yv[8];
#pragma unroll
        for (int i = 0; i < 8; i++) yv[i] = *reinterpret_cast<const u16x8*>(yb + i * 32);
        float t1 = 0.f, t2 = 0.f;
#pragma unroll
        for (int i = 0; i < 8; i++)
#pragma unroll
            for (int j = 0; j < 8; j++) {
                float tt = b2f(rv[i][j]) + b2f(yv[i][j]);
                t1 += tt; t2 += tt * tt;
            }
        t1 = grp4sum(t1); t2 = grp4sum(t2);
        float mean2 = t1 * (1.f / 256);
        float rs2 = rsqrtf(t2 * (1.f / 256) - mean2 * mean2 + 1e-5f);
        float* of = (float*)outp + grow * 256 + qd * 8;
        unsigned short* ob = (unsigned short*)outp + grow * 256 + qd * 8;
#pragma unroll
        for (int i = 0; i < 8; i++) {
            int cb = qd * 8 + i * 32;
            u16x8 gg = *reinterpret_cast<const u16x8*>(g1 + cb);
            u16x8 bb = *reinterpret_cast<const u16x8*>(b1 + cb);
            float rvals[8];
#pragma unroll
            for (int j = 0; j < 8; j++) {
                float tt = b2f(rv[i][j]) + b2f(yv[i][j]);
                rvals[j] = (tt - mean2) * rs2 * b2f(gg[j]) + b2f(bb[j]);
            }
            if (isb) {
                u16x8 o;
#pragma unroll
                for (int j = 0; j < 8; j++) o[j] = f2b(rvals[j]);
                *reinterpret_cast<u16x8*>(ob + i * 32) = o;
            } else {
                f32x4 o0, o1;
#pragma unroll
                for (int j = 0; j < 4; j++) { o0[j] = rvals[j]; o1[j] = rvals[4 + j]; }
                *reinterpret_cast<f32x4*>(of + i * 32) = o0;
                *reinterpret_cast<f32x4*>(of + i * 32 + 4) = o1;
            }
        }
    }
}

// ---------------- ctx partial (no-max exp): slab of 256 tokens per block ----------------
__global__ __launch_bounds__(256) void ctx_part_kernel(
    const unsigned short* __restrict__ n2, float* __restrict__ pctx,
    float* __restrict__ pcs)
{
    int blk = blockIdx.x;
    int b = blk >> 7, hd = (blk >> 4) & 7, slab = blk & 15;
    int t = threadIdx.x;
    __shared__ float ld[32][33], eld[32][33];
    int d = t >> 3;
    int v0 = (t & 7) << 2;
    int ln_ = t >> 3;
    int lc = (t & 7) << 2;
    f32x4 acc = {0.f, 0.f, 0.f, 0.f};
    float se = 0.f;
    const unsigned short* base = n2 + ((long)b * 4096 + slab * 256) * CC + hd * 32;
    for (int n0 = 0; n0 < 256; n0 += 32) {
        u16x4 rv = *reinterpret_cast<const u16x4*>(base + (long)(n0 + ln_) * CC + lc);
#pragma unroll
        for (int j = 0; j < 4; j++) {
            float x = b2f(rv[j]);
            ld[ln_][lc + j] = x;
            eld[ln_][lc + j] = __expf(x);
        }
        __syncthreads();
#pragma unroll 4
        for (int nn = 0; nn < 32; nn++) {
            float e = eld[nn][d];
            se += e;
#pragma unroll
            for (int j = 0; j < 4; j++) acc[j] += e * ld[nn][v0 + j];
        }
        __syncthreads();
    }
    long o = ((long)slab * NBATCH * 8 + (long)b * 8 + hd) * 1024 + (long)d * 32 + v0;
#pragma unroll
    for (int j = 0; j < 4; j++) pctx[o + j] = acc[j];
    if ((t & 7) == 0)
        pcs[(long)slab * (NBATCH * 8 * 32) + ((long)(b * 8 + hd) << 5) + d] = se;
}

// ---------------- ctx reduce: sum 16 slab partials, normalize by column sum ----------------
__global__ __launch_bounds__(256) void ctx_reduce_kernel(
    const float* __restrict__ pctx, const float* __restrict__ pcs,
    float* __restrict__ ctx)
{
    long i = (long)blockIdx.x * 256 + threadIdx.x;   // 65536 elems
    int bh = (int)(i >> 10);
    int d = (int)((i >> 5) & 31);
    float s = 0.f, ps = 0.f;
#pragma unroll
    for (int sl = 0; sl < 16; sl++) {
        s += pctx[(long)sl * 65536 + i];
        ps += pcs[(long)sl * (NBATCH * 8 * 32) + (bh << 5) + d];
    }
    ctx[i] = s / ps;
}

// ---------------- q-softmax + att = ctx^T q, barrier-free shuffle version ----------------
__global__ __launch_bounds__(256) void att_kernel(
    const unsigned short* __restrict__ n1, const float* __restrict__ ctx,
    unsigned short* __restrict__ attv)
{
    __shared__ float cl[32 * 256];   // [d][c]
    int b = blockIdx.x >> 6, grp = blockIdx.x & 63;
    int t = threadIdx.x, wid = t >> 6, l = t & 63;
    const float* cb = ctx + (long)b * 8192;
    for (int i = 0; i < 32; i++) {
        int gidx = t + (i << 8);
        int hd_ = gidx >> 10, dd = (gidx >> 5) & 31, vv = gidx & 31;
        cl[dd * 256 + hd_ * 32 + vv] = cb[gidx];
    }
    __syncthreads();
    int base_lane = l & 56;
    long tokbase = (long)b * 4096 + grp * 64 + wid * 16;
    const f32x4* c4 = reinterpret_cast<const f32x4*>(cl);
    for (int it = 0; it < 16; it++) {
        long tok = tokbase + it;
        u16x4 rv = *reinterpret_cast<const u16x4*>(n1 + tok * CC + l * 4);
        float x[4];
#pragma unroll
        for (int j = 0; j < 4; j++) x[j] = b2f(rv[j]);
        float mx = fmaxf(fmaxf(x[0], x[1]), fmaxf(x[2], x[3]));
        mx = fmaxf(mx, __shfl_xor(mx, 1));
        mx = fmaxf(mx, __shfl_xor(mx, 2));
        mx = fmaxf(mx, __shfl_xor(mx, 4));
        float e[4], s = 0.f;
#pragma unroll
        for (int j = 0; j < 4; j++) { e[j] = __expf(x[j] - mx); s += e[j]; }
        s += __shfl_xor(s, 1);
        s += __shfl_xor(s, 2);
        s += __shfl_xor(s, 4);
        float inv = 1.f / s;
        f32x4 o = {0.f, 0.f, 0.f, 0.f};
#pragma unroll
        for (int dd = 0; dd < 32; dd++) {
            float qv = __shfl(e[dd & 3], base_lane + (dd >> 2));
            o += qv * c4[dd * 64 + l];
        }
        o *= inv;
        u16x4 ov;
#pragma unroll
        for (int j = 0; j < 4; j++) ov[j] = f2b(o[j]);
        *reinterpret_cast<u16x4*>(attv + tok * CC + l * 4) = ov;
    }
}

// ---------------- depthwise 3x3 conv + LN + tanh-GELU (transposed weights, XCD swizzle) -------
__global__ __launch_bounds__(256) void dw_kernel(
    const unsigned short* __restrict__ h1, const unsigned short* __restrict__ dwt,
    const unsigned short* __restrict__ dwb, const unsigned short* __restrict__ g,
    const unsigned short* __restrict__ bb, unsigned short* __restrict__ ax, int nwg)
{
    int wid = threadIdx.x >> 6, l = threadIdx.x & 63;
    int bid = blockIdx.x, cpx = nwg >> 3;
    int wg = (bid & 7) * cpx + (bid >> 3);      // bijective XCD swizzle (nwg % 8 == 0)
    int pix = wg * 4 + wid;
    int b = pix >> 12, rem = pix & 4095, py = rem >> 6, px = rem & 63;
    int c0 = l * 8;
    u16x8 wv[9];
#pragma unroll
    for (int tap = 0; tap < 9; tap++)
        wv[tap] = *reinterpret_cast<const u16x8*>(dwt + tap * CC2 + c0);
    u16x8 biasv = *reinterpret_cast<const u16x8*>(dwb + c0);
    float acc[8];
#pragma unroll
    for (int j = 0; j < 8; j++) acc[j] = b2f(biasv[j]);
#pragma unroll
    for (int ky = 0; ky < 3; ky++) {
        int ys = py + ky - 1;
        if ((unsigned)ys >= 64u) continue;
#pragma unroll
        for (int kx = 0; kx < 3; kx++) {
            int xs = px + kx - 1;
            if ((unsigned)xs >= 64u) continue;
            u16x8 pv = *reinterpret_cast<const u16x8*>(
                h1 + ((long)(b << 12) + (ys << 6) + xs) * CC2 + c0);
            int tap = ky * 3 + kx;
#pragma unroll
            for (int j = 0; j < 8; j++)
                acc[j] += b2f(pv[j]) * b2f(wv[tap][j]);
        }
    }
    float s = 0.f;
#pragma unroll
    for (int j = 0; j < 8; j++) s += acc[j];
    float mean = wredsum(s) * (1.f / CC2);
    float d[8], sq = 0.f;
#pragma unroll
    for (int j = 0; j < 8; j++) { d[j] = acc[j] - mean; sq += d[j] * d[j]; }
    float rs = rsqrtf(wredsum(sq) * (1.f / CC2) + 1e-5f);
    u16x8 gv = *reinterpret_cast<const u16x8*>(g + c0);
    u16x8 bv = *reinterpret_cast<const u16x8*>(bb + c0);
    u16x8 o;
#pragma unroll
    for (int j = 0; j < 8; j++) {
        float nv = d[j] * rs * b2f(gv[j]) + b2f(bv[j]);
        float u = 1.59576912f * nv * (1.f + 0.044715f * nv * nv);
        float gl = nv / (1.f + __expf(-u));
        o[j] = f2b(gl);
    }
    *reinterpret_cast<u16x8*>(ax + (long)pix * CC2 + c0) = o;
}

extern "C" void kernel_launch(void* const* d_in, const int* in_sizes, int n_in,
                              void* d_out, int out_size, void* d_ws, size_t ws_size,
                              hipStream_t stream)
{
    char* w = (char*)d_ws;
    const size_t S1B = (size_t)BTOK * CC * 2;   // 16.78 MB
    const size_t STATSB = (size_t)(2 * NBATCH * CC + NBATCH * 8 * 32 * 32) * 4;
    const size_t PARAMS_ELEMS = 402688;
    const size_t need = 6 * S1B + STATSB + 64 + PARAMS_ELEMS * 2;
    if (ws_size < need) return;

    unsigned short* ln12 = (unsigned short*)w;
    unsigned short* n12  = (unsigned short*)(w + 2 * S1B);
    unsigned short* nn1  = n12;
    unsigned short* nn2  = n12 + (size_t)BTOK * CC;
    unsigned short* attv = ln12;
    unsigned short* ybuf = nn1;
    unsigned short* h1   = ln12;
    unsigned short* axb  = (unsigned short*)(w + 4 * S1B);
    float* pctx = (float*)(w + 4 * S1B + (2048 << 10));             // 4 MB
    float* pcs  = (float*)(w + 4 * S1B + (2048 << 10) + (4 << 20)); // 128 KB
    float* ctxb = (float*)(w + 6 * S1B) + 2 * NBATCH * CC;
    int*   flag = (int*)(w + 6 * S1B + STATSB);
    unsigned short* pb = (unsigned short*)(w + 6 * S1B + STATSB + 64);

    unsigned short* n1g  = pb + 0;
    unsigned short* n1b  = pb + 256;
    unsigned short* linw = pb + 512;
    unsigned short* linb = pb + 66048;
    unsigned short* repw = pb + 66304;
    unsigned short* repb = pb + 131840;
    unsigned short* ang  = pb + 132096;
    unsigned short* anb  = pb + 132352;
    unsigned short* g2   = pb + 132608;
    unsigned short* b2v  = pb + 132864;
    unsigned short* fc1w = pb + 133120;
    unsigned short* fc1b = pb + 264192;
    unsigned short* dwt  = pb + 264704;
    unsigned short* dwb  = pb + 269312;
    unsigned short* fn1g = pb + 269824;
    unsigned short* fn1b = pb + 270336;
    unsigned short* fc2w = pb + 270848;
    unsigned short* fc2b = pb + 401920;
    unsigned short* fn3g = pb + 402176;
    unsigned short* fn3b = pb + 402432;

    probe_kernel<<<1, 256, 0, stream>>>((const unsigned short*)d_in[0], flag);
    cvt_params_kernel<<<512, 256, 0, stream>>>(flag,
        d_in[2], d_in[3], d_in[4], d_in[5], d_in[6], d_in[7], d_in[8], d_in[9],
        d_in[10], d_in[11], d_in[12], d_in[13], d_in[14], d_in[15], d_in[16],
        d_in[17], d_in[18], d_in[19], d_in[20], d_in[21], pb);
    {   // fused LN1 + lin: T = 2*BTOK, O = 256
        int nwg = 2 * BTOK / 128;                  // 512
        lnlin_kernel<<<nwg, 1024, 0, stream>>>(
            d_in[0], d_in[1], n1g, n1b, linw, linb, n12, flag, nwg);
    }
    ctx_part_kernel<<<NBATCH * 8 * 16, 256, 0, stream>>>(nn2, pctx, pcs);
    ctx_reduce_kernel<<<256, 256, 0, stream>>>(pctx, pcs, ctxb);
    att_kernel<<<NBATCH * 64, 256, 0, stream>>>(nn1, ctxb, attv);
    {   // reproj + attnLN + x1 + LN2 -> ybuf
        int nwg = BTOK / 128;                      // 256
        gemm_fused_kernel<256, 0><<<nwg, 512, 0, stream>>>(
            attv, repw, repb, d_in[0], ang, anb, g2, b2v, ybuf, flag, nwg);
    }
    {   // fc1: T = BTOK, O = 512
        int nwg = (BTOK / 128) * (CC2 / 128);      // 1024
        gemm_lds_kernel<256><<<nwg, 256, 0, stream>>>(ybuf, fc1w, fc1b, h1, CC2, nwg);
    }
    dw_kernel<<<BTOK / 4, 256, 0, stream>>>(h1, dwt, dwb, fn1g, fn1b, axb, BTOK / 4);
    {   // fc2 + y + finalLN -> out
        int nwg = BTOK / 128;                      // 256
        gemm_fused_kernel<512, 1><<<nwg, 512, 0, stream>>>(
            axb, fc2w, fc2b, ybuf, fn3g, fn3b, fn3g, fn3b, d_out, flag, nwg);
    }
}